// Round 3
// baseline (324.894 us; speedup 1.0000x reference)
//
#include <hip/hip_runtime.h>

#define DEV __device__ __forceinline__

typedef __attribute__((ext_vector_type(8))) short short8v;
typedef __attribute__((ext_vector_type(4))) float f32x4;

DEV unsigned short f2bf(float f) {
  unsigned int x = __float_as_uint(f);
  x = x + 0x7FFFu + ((x >> 16) & 1u);   // RNE
  return (unsigned short)(x >> 16);
}

// ---- swizzled LDS tile: R rows x 64 bf16 (128 B/row, 8x16B chunks) ----
// LDS chunk c of row r holds global chunk c ^ (r&7)  (involution).
DEV int swz_byte(int row, int kElem) {
  int chunk = ((kElem >> 3) ^ (row & 7));
  return row * 128 + (chunk << 4) + ((kElem & 7) << 1);
}

// Stage ROUNDS*32 rows x 64 cols of bf16 (256-thread kernels).
template <int ROUNDS>
DEV void stage(const unsigned short* __restrict__ g, int ld,
               unsigned short* tile, int tid) {
  const int wave = tid >> 6, l = tid & 63;
#pragma unroll
  for (int p = 0; p < ROUNDS; ++p) {
    const int r = (p << 5) + (wave << 3) + (l >> 3);
    const int c = ((l & 7) ^ (r & 7)) << 3;              // pre-swizzled col
    const unsigned short* src = g + (long)r * ld + c;
#if __has_builtin(__builtin_amdgcn_global_load_lds)
    unsigned short* dst = tile + (p << 11) + (wave << 9);  // wave-uniform
    __builtin_amdgcn_global_load_lds(
        (const __attribute__((address_space(1))) void*)src,
        (__attribute__((address_space(3))) void*)dst, 16, 0, 0);
#else
    short8v v = *reinterpret_cast<const short8v*>(src);
    *reinterpret_cast<short8v*>(reinterpret_cast<char*>(tile) +
                                (p << 12) + (wave << 10) + (l << 4)) = v;
#endif
  }
}

// NT GEMM, bf16 inputs: C[M][N] = A[M][K] * B[N][K]^T. Tile BM x 128, BK=64.
// EPI: 0 -> store bf16, 1 -> store f32,
//      2 -> store f32 with scale+mask AND emit per-(row, n-tile) softmax
//           partial stats (max, sum-exp-rel-to-own-max).
template <int BM, int EPI>
__global__ __launch_bounds__(256) void gemm_bf16(
    const unsigned short* __restrict__ A, const unsigned short* __restrict__ B,
    void* __restrict__ Cout, int M, int N, int K,
    long aBatch, long bBatch, long cBatch,
    const int* __restrict__ srcMask, const int* __restrict__ melMask,
    float scale, float* __restrict__ stats) {
  constexpr int NI = BM / 32;
  __shared__ unsigned short As[BM * 64];
  __shared__ unsigned short Bs[128 * 64];
  const int tid = threadIdx.x;
  const int lane = tid & 63;
  const int wave = tid >> 6;
  const int z = blockIdx.z;
  const unsigned short* Ab = A + (long)z * aBatch;
  const unsigned short* Bb = B + (long)z * bBatch;
  const long cOff = (long)z * cBatch;
  const int bm = blockIdx.y * BM;
  const int bn = blockIdx.x * 128;
  const int wr = (wave >> 1) * (BM / 2);
  const int wc = (wave & 1) * 64;
  const int l15 = lane & 15;
  const int lHi = lane >> 4;

  f32x4 acc[NI][4] = {};

  for (int kt = 0; kt < K; kt += 64) {
    stage<BM / 32>(Ab + (long)bm * K + kt, K, As, tid);
    stage<4>(Bb + (long)bn * K + kt, K, Bs, tid);
    __syncthreads();
#pragma unroll
    for (int ks = 0; ks < 2; ++ks) {
      const int k0 = (ks << 5) + (lHi << 3);
      short8v af[NI], bfr[4];
#pragma unroll
      for (int i = 0; i < NI; ++i)
        af[i] = *reinterpret_cast<const short8v*>(
            reinterpret_cast<const char*>(As) + swz_byte(wr + i * 16 + l15, k0));
#pragma unroll
      for (int j = 0; j < 4; ++j)
        bfr[j] = *reinterpret_cast<const short8v*>(
            reinterpret_cast<const char*>(Bs) + swz_byte(wc + j * 16 + l15, k0));
#pragma unroll
      for (int i = 0; i < NI; ++i)
#pragma unroll
        for (int j = 0; j < 4; ++j)
          acc[i][j] = __builtin_amdgcn_mfma_f32_16x16x32_bf16(af[i], bfr[j], acc[i][j], 0, 0, 0);
    }
    __syncthreads();
  }

  if constexpr (EPI == 2) {
    __shared__ float redM[128][2];
    __shared__ float redS[128][2];
    const int wcIdx = wave & 1;
#pragma unroll
    for (int i = 0; i < NI; ++i) {
#pragma unroll
      for (int rr = 0; rr < 4; ++rr) {
        const int rloc = wr + i * 16 + lHi * 4 + rr;
        const int rb = bm + rloc;
        const bool sm = srcMask[z * 1024 + rb] != 0;
        float vals[4];
        float m_l = -3.0e38f;
#pragma unroll
        for (int j = 0; j < 4; ++j) {
          const int c = bn + wc + j * 16 + l15;
          const bool mm = melMask[z * 2048 + c] != 0;
          const float vf = (sm && mm) ? -1e30f : acc[i][j][rr] * scale;
          vals[j] = vf;
          reinterpret_cast<float*>(Cout)[cOff + (long)rb * N + c] = vf;
          m_l = fmaxf(m_l, vf);
        }
#pragma unroll
        for (int o = 1; o < 16; o <<= 1) m_l = fmaxf(m_l, __shfl_xor(m_l, o, 64));
        float s_l = 0.f;
#pragma unroll
        for (int j = 0; j < 4; ++j) s_l += __expf(vals[j] - m_l);
#pragma unroll
        for (int o = 1; o < 16; o <<= 1) s_l += __shfl_xor(s_l, o, 64);
        if (l15 == 0) { redM[rloc][wcIdx] = m_l; redS[rloc][wcIdx] = s_l; }
      }
    }
    __syncthreads();
    if (tid < 128) {
      const float m0 = redM[tid][0], m1 = redM[tid][1];
      const float Mx = fmaxf(m0, m1);
      const float S = redS[tid][0] * __expf(m0 - Mx) + redS[tid][1] * __expf(m1 - Mx);
      const long sidx = ((long)(z * 1024 + bm + tid)) * 32 + (long)blockIdx.x * 2;
      stats[sidx] = Mx;
      stats[sidx + 1] = S;
    }
  } else {
#pragma unroll
    for (int i = 0; i < NI; ++i) {
#pragma unroll
      for (int j = 0; j < 4; ++j) {
        const int rb = bm + wr + i * 16 + lHi * 4;
        const int c = bn + wc + j * 16 + l15;
#pragma unroll
        for (int r = 0; r < 4; ++r) {
          const float v = acc[i][j][r];
          const long idx = cOff + (long)(rb + r) * N + c;
          if constexpr (EPI == 0)
            reinterpret_cast<unsigned short*>(Cout)[idx] = f2bf(v);
          else
            reinterpret_cast<float*>(Cout)[idx] = v;
        }
      }
    }
  }
}

// Fused softmax + PV. One block = 64 Q-rows x full N=512. 512 threads.
// Reads raw masked scores (fp32), combines per-tile stats, writes normalized
// attn fp32 in place, accumulates out = P @ vT^T with bf16 MFMA.
__global__ __launch_bounds__(512) void softmax_pv(
    float* __restrict__ attn, const unsigned short* __restrict__ vT,
    float* __restrict__ out, const float* __restrict__ stats) {
  __shared__ unsigned short As[64 * 64];    // 8 KB, swizzled P-chunk
  __shared__ unsigned short Bs[512 * 64];   // 64 KB, swizzled vT-chunk
  __shared__ float rowM[64], rowInv[64];
  const int z = blockIdx.x;                 // batch (x so same-batch -> same XCD)
  const int bm = blockIdx.y * 64;
  const int tid = threadIdx.x, lane = tid & 63, wave = tid >> 6;
  const long sOff = ((long)z * 1024 + bm) * 2048;

  if (tid < 64) {
    const float* st = stats + ((long)(z * 1024 + bm + tid)) * 32;
    float Mx = -3.0e38f;
#pragma unroll
    for (int t = 0; t < 16; ++t) Mx = fmaxf(Mx, st[t * 2]);
    float S = 0.f;
#pragma unroll
    for (int t = 0; t < 16; ++t) S += st[t * 2 + 1] * __expf(st[t * 2] - Mx);
    rowM[tid] = Mx;
    rowInv[tid] = 1.0f / S;
  }
  __syncthreads();

  const int r = tid >> 3;                   // A-stage row 0..63
  const int c8 = (tid & 7) << 3;            // A-stage col base
  const float mR = rowM[r];
  const float invR = rowInv[r];
  const int wr2 = (wave >> 2) * 32;
  const int wc2 = (wave & 3) * 128;
  const int l15 = lane & 15, lHi = lane >> 4;

  f32x4 acc[2][8] = {};

  for (int kt = 0; kt < 2048; kt += 64) {
    // ---- A stage: normalize, write attn in place, pack bf16 to LDS ----
    {
      float* sp = attn + sOff + (long)r * 2048 + kt + c8;
      const float4 x0 = *reinterpret_cast<const float4*>(sp);
      const float4 x1 = *reinterpret_cast<const float4*>(sp + 4);
      float4 e0, e1;
      e0.x = __expf(x0.x - mR) * invR; e0.y = __expf(x0.y - mR) * invR;
      e0.z = __expf(x0.z - mR) * invR; e0.w = __expf(x0.w - mR) * invR;
      e1.x = __expf(x1.x - mR) * invR; e1.y = __expf(x1.y - mR) * invR;
      e1.z = __expf(x1.z - mR) * invR; e1.w = __expf(x1.w - mR) * invR;
      *reinterpret_cast<float4*>(sp) = e0;
      *reinterpret_cast<float4*>(sp + 4) = e1;
      short8v pk;
      pk[0] = (short)f2bf(e0.x); pk[1] = (short)f2bf(e0.y);
      pk[2] = (short)f2bf(e0.z); pk[3] = (short)f2bf(e0.w);
      pk[4] = (short)f2bf(e1.x); pk[5] = (short)f2bf(e1.y);
      pk[6] = (short)f2bf(e1.z); pk[7] = (short)f2bf(e1.w);
      *reinterpret_cast<short8v*>(reinterpret_cast<char*>(As) + r * 128 +
                                  ((((tid & 7) ^ (r & 7))) << 4)) = pk;
    }
    // ---- B stage: vT rows 0..511 x 64 k-cols via global_load_lds ----
#pragma unroll
    for (int p = 0; p < 8; ++p) {
      const int r2 = (p << 6) + (wave << 3) + (lane >> 3);
      const int cc = ((lane & 7) ^ (r2 & 7)) << 3;
      const unsigned short* srcB = vT + (long)z * 512 * 2048 + (long)r2 * 2048 + kt + cc;
#if __has_builtin(__builtin_amdgcn_global_load_lds)
      unsigned short* dst = Bs + ((p << 6) + (wave << 3)) * 64;
      __builtin_amdgcn_global_load_lds(
          (const __attribute__((address_space(1))) void*)srcB,
          (__attribute__((address_space(3))) void*)dst, 16, 0, 0);
#else
      short8v v = *reinterpret_cast<const short8v*>(srcB);
      *reinterpret_cast<short8v*>(reinterpret_cast<char*>(Bs) +
                                  ((p << 6) + (wave << 3)) * 128 + (lane << 4)) = v;
#endif
    }
    __syncthreads();
#pragma unroll
    for (int ks = 0; ks < 2; ++ks) {
      const int k0 = (ks << 5) + (lHi << 3);
      short8v af[2], bfr[8];
#pragma unroll
      for (int i = 0; i < 2; ++i)
        af[i] = *reinterpret_cast<const short8v*>(
            reinterpret_cast<const char*>(As) + swz_byte(wr2 + i * 16 + l15, k0));
#pragma unroll
      for (int j = 0; j < 8; ++j)
        bfr[j] = *reinterpret_cast<const short8v*>(
            reinterpret_cast<const char*>(Bs) + swz_byte(wc2 + j * 16 + l15, k0));
#pragma unroll
      for (int i = 0; i < 2; ++i)
#pragma unroll
        for (int j = 0; j < 8; ++j)
          acc[i][j] = __builtin_amdgcn_mfma_f32_16x16x32_bf16(af[i], bfr[j], acc[i][j], 0, 0, 0);
    }
    __syncthreads();
  }

#pragma unroll
  for (int i = 0; i < 2; ++i)
#pragma unroll
    for (int j = 0; j < 8; ++j) {
      const int row = bm + wr2 + i * 16 + lHi * 4;
      const int col = wc2 + j * 16 + l15;
#pragma unroll
      for (int rr = 0; rr < 4; ++rr)
        out[((long)z * 1024 + row + rr) * 512 + col] = acc[i][j][rr];
    }
}

// fp32 -> bf16 elementwise, 8 elems/thread, grid-stride.
__global__ __launch_bounds__(256) void f32_to_bf16(
    const float* __restrict__ in, unsigned short* __restrict__ out, long n) {
  long i = ((long)blockIdx.x * blockDim.x + threadIdx.x) * 8;
  const long stride = (long)gridDim.x * blockDim.x * 8;
  for (; i < n; i += stride) {
    const float4 a = *reinterpret_cast<const float4*>(in + i);
    const float4 b = *reinterpret_cast<const float4*>(in + i + 4);
    short8v o;
    o[0] = (short)f2bf(a.x); o[1] = (short)f2bf(a.y);
    o[2] = (short)f2bf(a.z); o[3] = (short)f2bf(a.w);
    o[4] = (short)f2bf(b.x); o[5] = (short)f2bf(b.y);
    o[6] = (short)f2bf(b.z); o[7] = (short)f2bf(b.w);
    *reinterpret_cast<short8v*>(out + i) = o;
  }
}

// Transpose+convert the three 512x512 fp32 weights to bf16 W^T.
__global__ __launch_bounds__(256) void transpose_w3(
    const float* __restrict__ Wq, const float* __restrict__ Wk, const float* __restrict__ Wv,
    unsigned short* __restrict__ WqT, unsigned short* __restrict__ WkT,
    unsigned short* __restrict__ WvT) {
  __shared__ float t[32][33];
  const int zz = blockIdx.z;
  const float* W = zz == 0 ? Wq : zz == 1 ? Wk : Wv;
  unsigned short* WT = zz == 0 ? WqT : zz == 1 ? WkT : WvT;
  const int bx = blockIdx.x * 32;
  const int by = blockIdx.y * 32;
  const int tx = threadIdx.x, ty = threadIdx.y;  // (32,8)
#pragma unroll
  for (int i = 0; i < 4; ++i)
    t[ty + i * 8][tx] = W[(long)(by + ty + i * 8) * 512 + bx + tx];
  __syncthreads();
#pragma unroll
  for (int i = 0; i < 4; ++i)
    WT[(long)(bx + ty + i * 8) * 512 + by + tx] = f2bf(t[tx][ty + i * 8]);
}

// In-place LayerNorm over rows of 512 fp32. One wave per row.
__global__ __launch_bounds__(64) void layernorm_rows(
    float* __restrict__ out, const float* __restrict__ gamma, const float* __restrict__ beta) {
  const long row = blockIdx.x;
  float4* p = reinterpret_cast<float4*>(out + row * 512);
  const int lane = threadIdx.x;
  float4 a = p[lane];
  float4 b = p[lane + 64];
  float s = ((a.x + a.y) + (a.z + a.w)) + ((b.x + b.y) + (b.z + b.w));
  float s2 = ((a.x * a.x + a.y * a.y) + (a.z * a.z + a.w * a.w)) +
             ((b.x * b.x + b.y * b.y) + (b.z * b.z + b.w * b.w));
#pragma unroll
  for (int o = 32; o; o >>= 1) {
    s += __shfl_xor(s, o, 64);
    s2 += __shfl_xor(s2, o, 64);
  }
  const float mean = s * (1.0f / 512.0f);
  const float var = s2 * (1.0f / 512.0f) - mean * mean;
  const float rstd = rsqrtf(var + 1e-5f);
  const float4 g0 = reinterpret_cast<const float4*>(gamma)[lane];
  const float4 g1 = reinterpret_cast<const float4*>(gamma)[lane + 64];
  const float4 c0 = reinterpret_cast<const float4*>(beta)[lane];
  const float4 c1 = reinterpret_cast<const float4*>(beta)[lane + 64];
  a.x = (a.x - mean) * rstd * g0.x + c0.x;
  a.y = (a.y - mean) * rstd * g0.y + c0.y;
  a.z = (a.z - mean) * rstd * g0.z + c0.z;
  a.w = (a.w - mean) * rstd * g0.w + c0.w;
  b.x = (b.x - mean) * rstd * g1.x + c1.x;
  b.y = (b.y - mean) * rstd * g1.y + c1.y;
  b.z = (b.z - mean) * rstd * g1.z + c1.z;
  b.w = (b.w - mean) * rstd * g1.w + c1.w;
  p[lane] = a;
  p[lane + 64] = b;
}

extern "C" void kernel_launch(void* const* d_in, const int* in_sizes, int n_in,
                              void* d_out, int out_size, void* d_ws, size_t ws_size,
                              hipStream_t stream) {
  const float* mel  = (const float*)d_in[0];   // [16,2048,512]
  const float* text = (const float*)d_in[1];   // [16,1024,512]
  const int* melMask = (const int*)d_in[2];    // [16,2048]
  const int* srcMask = (const int*)d_in[3];    // [16,1024]
  const float* Wq = (const float*)d_in[4];
  const float* Wk = (const float*)d_in[5];
  const float* Wv = (const float*)d_in[6];
  const float* gamma = (const float*)d_in[7];
  const float* beta  = (const float*)d_in[8];

  float* out = (float*)d_out;                           // [16,1024,512]
  float* attn = (float*)d_out + (long)16 * 1024 * 512;  // [16,1024,2048]

  unsigned short* ws = (unsigned short*)d_ws;
  unsigned short* wqT = ws;
  unsigned short* wkT = wqT + 512 * 512;
  unsigned short* wvT = wkT + 512 * 512;
  unsigned short* melbf  = wvT + 512 * 512;               // 16*2048*512
  unsigned short* textbf = melbf + (long)16 * 2048 * 512; // 16*1024*512
  unsigned short* qbf = textbf + (long)16 * 1024 * 512;
  unsigned short* kbf = qbf + (long)16 * 1024 * 512;
  unsigned short* vT  = kbf + (long)16 * 2048 * 512;      // 16*512*2048
  // stats [16][1024][16][2] fp32 aliases textbf (dead after q-GEMM).
  float* stats = (float*)textbf;

  transpose_w3<<<dim3(16, 16, 3), dim3(32, 8), 0, stream>>>(Wq, Wk, Wv, wqT, wkT, wvT);
  f32_to_bf16<<<dim3(4096), 256, 0, stream>>>(mel, melbf, (long)16 * 2048 * 512);
  f32_to_bf16<<<dim3(2048), 256, 0, stream>>>(text, textbf, (long)16 * 1024 * 512);

  // q = text @ Wq   (bf16 out) -- must precede scores (stats aliases textbf)
  gemm_bf16<128, 0><<<dim3(4, 128, 1), 256, 0, stream>>>(
      textbf, wqT, qbf, 16384, 512, 512, 0, 0, 0, nullptr, nullptr, 1.0f, nullptr);
  // k = mel @ Wk
  gemm_bf16<128, 0><<<dim3(4, 256, 1), 256, 0, stream>>>(
      melbf, wkT, kbf, 32768, 512, 512, 0, 0, 0, nullptr, nullptr, 1.0f, nullptr);
  // vT[b][m][s]
  gemm_bf16<128, 0><<<dim3(16, 4, 16), 256, 0, stream>>>(
      wvT, melbf, vT, 512, 2048, 512, 0, (long)2048 * 512, (long)512 * 2048,
      nullptr, nullptr, 1.0f, nullptr);
  // raw masked scores (fp32) + partial softmax stats
  gemm_bf16<128, 2><<<dim3(16, 8, 16), 256, 0, stream>>>(
      qbf, kbf, attn, 1024, 2048, 512,
      (long)1024 * 512, (long)2048 * 512, (long)1024 * 2048,
      srcMask, melMask, 0.044194173824159216f, stats);
  // fused softmax + PV (in-place attn normalize + out accumulate)
  softmax_pv<<<dim3(16, 16), 512, 0, stream>>>(attn, vT, out, stats);
  layernorm_rows<<<dim3(16 * 1024), 64, 0, stream>>>(out, gamma, beta);
}